// Round 3
// baseline (390.482 us; speedup 1.0000x reference)
//
#include <hip/hip_runtime.h>

// Morphological opening: dilate3x3(erode3x3(x)), flat SE, SAME padding.
// v6: max-TLP redesign. Two rounds of evidence (VGPR=32/40, VALUBusy ~13%,
// HBM ~32%, occupancy ~52%) showed the rolling-window kernel is latency-bound:
// the compiler refuses to keep the prefetch ring live (branchy load helpers
// fragment scheduling regions; loads sink to uses), and 3072 blocks give only
// ~4 resident blocks/CU. This version drops all cross-iteration state:
//   - one output row per thread; 10 independent float4 loads, one store
//   - single straight-line branchless body (selects only, no branches)
//   - grid = 49152 blocks -> 192 waves/SIMD of TLP; latency hidden by waves
//   - XCD-swizzled rows: each XCD gets contiguous 128-row chunks per image,
//     so the 5x cross-block row reuse is served by its own L2.
//
// Semantics: erosion pads OOB *inputs* with +inf (identity for min);
// erosion values at OOB *positions* enter the dilation max as -inf.

#define W 1024
#define H 1024
#define NT 256

typedef float nvec4 __attribute__((ext_vector_type(4)));  // nontemporal store vector

__global__ __launch_bounds__(NT)
void open3x3_v6(const float* __restrict__ in, float* __restrict__ out) {
    const int t  = threadIdx.x;
    const int c0 = 4 * t;                     // thread owns cols [c0, c0+4)
    // bx -> output row, XCD-chunked: XCD k owns rows [128k, 128k+128)
    const int bx = blockIdx.x;                // 0..1023
    const int y  = (bx & 7) * (H / 8) + (bx >> 3);
    const size_t imgoff = (size_t)blockIdx.y * (size_t)(W * H);
    const float* img  = in  + imgoff;
    float*       outp = out + imgoff;

    const float PINF = __builtin_inff();
    const float NINF = -__builtin_inff();
    const bool has_l = (c0 > 0);              // position c0-1 valid; col c0-2 exists
    const bool has_r = (c0 + 4 < W);          // position c0+4 valid; col c0+5 exists
    const int  cla   = has_l ? c0 - 2 : 0;    // clamped 8B-aligned halo bases
    const int  crb   = has_r ? c0 + 2 : W - 4;

    // ---- issue all 10 loads (5 rows x 2 overlapping float4), clamped rows ----
    float4 A[5], B[5];
    #pragma unroll
    for (int i = 0; i < 5; i++) {
        int r  = y - 2 + i;
        int rc = r < 0 ? 0 : (r > H - 1 ? H - 1 : r);
        const float* p = img + rc * W;
        A[i] = *(const float4*)(p + cla);
        B[i] = *(const float4*)(p + crb);
    }

    // ---- horizontal 3-min per row -> hm[i][0..5] at positions c0-1..c0+4 ----
    // OOB input rows (clamped loads) are forced to +inf (erosion identity).
    float hm[5][6];
    #pragma unroll
    for (int i = 0; i < 5; i++) {
        const int r = y - 2 + i;
        const bool rok = (r >= 0) && (r <= H - 1);   // rows 0,1,3,4 can be OOB
        const float x0 = has_l ? A[i].x : PINF;
        const float x1 = has_l ? A[i].y : PINF;
        const float x2 = has_l ? A[i].z : A[i].x;
        const float x3 = has_l ? A[i].w : A[i].y;
        const float x4 = has_r ? B[i].x : B[i].z;
        const float x5 = has_r ? B[i].y : B[i].w;
        const float x6 = has_r ? B[i].z : PINF;
        const float x7 = has_r ? B[i].w : PINF;
        float h0 = fminf(fminf(x0, x1), x2);
        float h1 = fminf(fminf(x1, x2), x3);
        float h2 = fminf(fminf(x2, x3), x4);
        float h3 = fminf(fminf(x3, x4), x5);
        float h4 = fminf(fminf(x4, x5), x6);
        float h5 = fminf(fminf(x5, x6), x7);
        hm[i][0] = rok ? h0 : PINF;
        hm[i][1] = rok ? h1 : PINF;
        hm[i][2] = rok ? h2 : PINF;
        hm[i][3] = rok ? h3 : PINF;
        hm[i][4] = rok ? h4 : PINF;
        hm[i][5] = rok ? h5 : PINF;
    }

    // ---- erosion rows y-1, y, y+1 at positions c0-1..c0+4 ----
    // OOB erosion *positions* (row or col) contribute -inf to the dilation max.
    float e[3][6];
    #pragma unroll
    for (int j = 0; j < 3; j++) {
        const int ey = y - 1 + j;
        const bool eok = (ey >= 0) && (ey <= H - 1);
        #pragma unroll
        for (int i = 0; i < 6; i++) {
            float v = fminf(fminf(hm[j][i], hm[j + 1][i]), hm[j + 2][i]);
            e[j][i] = eok ? v : NINF;
        }
        if (!has_l) e[j][0] = NINF;
        if (!has_r) e[j][5] = NINF;
    }

    // ---- dilation: horizontal 3-max then vertical 3-max ----
    nvec4 o;
    #pragma unroll
    for (int i = 0; i < 4; i++) {
        float h0 = fmaxf(fmaxf(e[0][i], e[0][i + 1]), e[0][i + 2]);
        float h1 = fmaxf(fmaxf(e[1][i], e[1][i + 1]), e[1][i + 2]);
        float h2 = fmaxf(fmaxf(e[2][i], e[2][i + 1]), e[2][i + 2]);
        o[i] = fmaxf(fmaxf(h0, h1), h2);
    }
    __builtin_nontemporal_store(o, (nvec4*)(outp + (size_t)y * W + c0));
}

extern "C" void kernel_launch(void* const* d_in, const int* in_sizes, int n_in,
                              void* d_out, int out_size, void* d_ws, size_t ws_size,
                              hipStream_t stream) {
    const float* x = (const float*)d_in[0];
    float* out = (float*)d_out;
    // one block = one full image row (256 threads x 4 cols); 48 images
    dim3 grid(H, 48);
    dim3 block(NT);
    open3x3_v6<<<grid, block, 0, stream>>>(x, out);
}

// Round 6
// 338.004 us; speedup vs baseline: 1.1553x; 1.1553x over previous
//
#include <hip/hip_runtime.h>

// Morphological opening: dilate3x3(erode3x3(x)), flat SE, SAME padding.
// v9: LDS row-ring + global_load_lds + counted vmcnt + raw s_barrier
// (m201/T3-T4 template shape). v4-v6 showed hipcc sinks VGPR-dest loads
// (VGPR 24-40 => pipeline collapsed, latency-bound at ~126us); v8 showed
// asm-pinned VGPR pipelines spill in-flight registers under pressure
// (absmax 0.999). global_load_lds has NO register destination: unsinkable,
// unspillable. Block covers full 1024-col rows (column halo read from LDS,
// zero halo loads). Ring = 8 rows x 4KB = 32KB -> 5 blocks/CU.
// Per-wave vmcnt FIFO: each iter = {1 stage, 1 store}; row y+2 was staged
// 4 iters ago => steady WAITV(8), ramp 4/5/6/7/8 (verified op-by-op).
// Slot reuse: stage at iter k writes slot (k+6)&7 whose previous row
// (y0+k-2) was consumed at iter k-4 (or prologue). Tail iters re-stage the
// last row (never read) to keep the vmcnt count uniform.
//
// Semantics: erosion pads OOB *inputs* with +inf (identity for min);
// erosion values at OOB *positions* enter the dilation max as -inf.

#define W 1024
#define H 1024
#define ROWS 16
#define NTILE (H / ROWS)   // 64 row-tiles per image
#define NT 256
#define RING 8

typedef float f4 __attribute__((ext_vector_type(4)));
typedef float f2 __attribute__((ext_vector_type(2)));

#define WAITV(N) do { asm volatile("s_waitcnt vmcnt(" #N ")" ::: "memory"); \
                      __builtin_amdgcn_sched_barrier(0); } while (0)
#define BAR()    do { __builtin_amdgcn_s_barrier(); \
                      __builtin_amdgcn_sched_barrier(0); } while (0)

__global__ __launch_bounds__(NT)
void open3x3_v9(const float* __restrict__ in, float* __restrict__ out) {
    __shared__ float smem[RING][W];          // 8 rows x 4KB = 32KB

    const int t  = threadIdx.x;
    const int c0 = 4 * t;                    // thread owns cols [c0, c0+4)
    const int bx = blockIdx.x;
    const int tile = (bx & 7) * (NTILE / 8) + (bx >> 3);   // XCD-chunked
    const int y0 = tile * ROWS;              // y0 % 8 == 0 -> slot(r) = r & 7
    const size_t imgoff = (size_t)blockIdx.y * (size_t)(W * H);
    const float* img  = in  + imgoff;
    float*       outp = out + imgoff;

    const float PINF = __builtin_inff();
    const float NINF = -__builtin_inff();
    const bool has_l = (c0 > 0);
    const bool has_r = (c0 + 4 < W);

    const int q = t >> 6;                    // wave id: wave q stages quarter q

    // Stage row r (clamped) into ring slot: one global_load_lds per wave,
    // LDS dest = wave-uniform base + lane*16 (linear), global src matches.
    auto stage = [&](int r, int slot) {
        int rc = r < 0 ? 0 : (r > H - 1 ? H - 1 : r);
        const float* gp = img + (size_t)rc * W + c0;          // 16B per lane
        float* lp = &smem[slot][q * 256];                     // wave-uniform
        __builtin_amdgcn_global_load_lds(gp, lp, 16, 0, 0);
    };

    // Horizontal 3-min of staged row -> hm[0..5] at positions c0-1..c0+4.
    // OOB rows (clamped duplicates in LDS) masked to +inf here.
    auto hminLDS = [&](int r, int slot, float hm[6]) {
        const float* rowp = &smem[slot][0];
        const bool rok = (r >= 0) && (r <= H - 1);
        f4 m  = *(const f4*)(rowp + c0);                      // ds_read_b128
        f2 L  = *(const f2*)(rowp + (has_l ? c0 - 2 : 0));    // ds_read_b64
        f2 Rr = *(const f2*)(rowp + (has_r ? c0 + 4 : W - 2));
        const float x0 = has_l ? L.x : PINF;
        const float x1 = has_l ? L.y : PINF;
        const float x2 = m.x, x3 = m.y, x4 = m.z, x5 = m.w;
        const float x6 = has_r ? Rr.x : PINF;
        const float x7 = has_r ? Rr.y : PINF;
        hm[0] = rok ? fminf(fminf(x0, x1), x2) : PINF;
        hm[1] = rok ? fminf(fminf(x1, x2), x3) : PINF;
        hm[2] = rok ? fminf(fminf(x2, x3), x4) : PINF;
        hm[3] = rok ? fminf(fminf(x3, x4), x5) : PINF;
        hm[4] = rok ? fminf(fminf(x4, x5), x6) : PINF;
        hm[5] = rok ? fminf(fminf(x5, x6), x7) : PINF;
    };

    // Erosion row r at positions c0-1..c0+4; OOB row/col positions -> -inf.
    auto erow = [&](int r, const float a[6], const float b[6], const float c[6], float e[6]) {
        const bool eok = (r >= 0) && (r <= H - 1);
        #pragma unroll
        for (int i = 0; i < 6; i++) {
            float v = fminf(fminf(a[i], b[i]), c[i]);
            e[i] = eok ? v : NINF;
        }
        if (!has_l) e[0] = NINF;
        if (!has_r) e[5] = NINF;
    };

    auto hmax4 = [&](const float e[6], float hx[4]) {
        #pragma unroll
        for (int i = 0; i < 4; i++) hx[i] = fmaxf(fmaxf(e[i], e[i + 1]), e[i + 2]);
    };

    // ---- prologue: stage rows y0-2..y0+5 into slots 6,7,0,1,2,3,4,5 ----
    stage(y0 - 2, 6); stage(y0 - 1, 7);
    stage(y0 + 0, 0); stage(y0 + 1, 1);
    stage(y0 + 2, 2); stage(y0 + 3, 3);
    stage(y0 + 4, 4); stage(y0 + 5, 5);
    WAITV(4);                                // rows y0-2..y0+1 resident
    BAR();

    float hmA[6], hmB[6], hmC[6], hmD[6];
    hminLDS(y0 - 2, 6, hmA); hminLDS(y0 - 1, 7, hmB);
    hminLDS(y0,     0, hmC); hminLDS(y0 + 1, 1, hmD);
    float e[6], hx0[4], hx1[4], hx2[4];
    erow(y0 - 1, hmA, hmB, hmC, e); hmax4(e, hx0);
    erow(y0,     hmB, hmC, hmD, e); hmax4(e, hx1);
    float hmP[6], hmQ[6], hmR[6];
    #pragma unroll
    for (int i = 0; i < 6; i++) { hmP[i] = hmC[i]; hmQ[i] = hmD[i]; }

    // ---- main loop: stage(y+6) -> counted wait -> barrier -> consume(y+2) ----
    #pragma unroll
    for (int k = 0; k < ROWS; k++) {
        const int y = y0 + k;
        int rn = y + 6;                      // tail: re-stage last row (never
        if (rn > y0 + ROWS + 1) rn = y0 + ROWS + 1;   // read) for uniform count
        stage(rn, (k + 6) & 7);

        if (k == 0)      WAITV(4);           // row y+2 staged 4 iters ago
        else if (k == 1) WAITV(5);
        else if (k == 2) WAITV(6);
        else if (k == 3) WAITV(7);
        else             WAITV(8);
        BAR();

        hminLDS(y + 2, (k + 2) & 7, hmR);
        erow(y + 1, hmP, hmQ, hmR, e);
        hmax4(e, hx2);

        f4 o;
        o.x = fmaxf(fmaxf(hx0[0], hx1[0]), hx2[0]);
        o.y = fmaxf(fmaxf(hx0[1], hx1[1]), hx2[1]);
        o.z = fmaxf(fmaxf(hx0[2], hx1[2]), hx2[2]);
        o.w = fmaxf(fmaxf(hx0[3], hx1[3]), hx2[3]);
        __builtin_nontemporal_store(o, (f4*)(outp + (size_t)y * W + c0));

        #pragma unroll
        for (int i = 0; i < 4; i++) { hx0[i] = hx1[i]; hx1[i] = hx2[i]; }
        #pragma unroll
        for (int i = 0; i < 6; i++) { hmP[i] = hmQ[i]; hmQ[i] = hmR[i]; }
    }
}

extern "C" void kernel_launch(void* const* d_in, const int* in_sizes, int n_in,
                              void* d_out, int out_size, void* d_ws, size_t ws_size,
                              hipStream_t stream) {
    const float* x = (const float*)d_in[0];
    float* out = (float*)d_out;
    // 16 batch * 3 channels = 48 images; 64 row-tiles per image -> 3072 blocks
    dim3 grid(NTILE, 48);
    dim3 block(NT);
    open3x3_v9<<<grid, block, 0, stream>>>(x, out);
}

// Round 7
// 330.728 us; speedup vs baseline: 1.1807x; 1.0220x over previous
//
#include <hip/hip_runtime.h>

// Morphological opening: dilate3x3(erode3x3(x)), flat SE, SAME padding.
// v10: v9 with ONE change — regular cached stores instead of
// __builtin_nontemporal_store. Evidence: v4/v5/v6/v9 (four structures:
// serialized per-wave, max-TLP, LDS counted-vmcnt pipeline) all plateau at
// 122-127us / ~2.7 TB/s combined, while this session's fillBufferAligned
// sustains 6.5 TB/s write-only. Common factor: NT stores whose vmcnt
// retirement (deep ack, L2 bypassed) sits inside every wait window —
// v9's WAITV(8) explicitly, v4/v5's compiler waits implicitly. Regular
// stores retire at L2 accept; writeback of full 128B lines is efficient
// (fill proves it). Everything else is byte-identical to v9.
//
// Semantics: erosion pads OOB *inputs* with +inf (identity for min);
// erosion values at OOB *positions* enter the dilation max as -inf.

#define W 1024
#define H 1024
#define ROWS 16
#define NTILE (H / ROWS)   // 64 row-tiles per image
#define NT 256
#define RING 8

typedef float f4 __attribute__((ext_vector_type(4)));
typedef float f2 __attribute__((ext_vector_type(2)));

#define WAITV(N) do { asm volatile("s_waitcnt vmcnt(" #N ")" ::: "memory"); \
                      __builtin_amdgcn_sched_barrier(0); } while (0)
#define BAR()    do { __builtin_amdgcn_s_barrier(); \
                      __builtin_amdgcn_sched_barrier(0); } while (0)

__global__ __launch_bounds__(NT)
void open3x3_v10(const float* __restrict__ in, float* __restrict__ out) {
    __shared__ float smem[RING][W];          // 8 rows x 4KB = 32KB

    const int t  = threadIdx.x;
    const int c0 = 4 * t;                    // thread owns cols [c0, c0+4)
    const int bx = blockIdx.x;
    const int tile = (bx & 7) * (NTILE / 8) + (bx >> 3);   // XCD-chunked
    const int y0 = tile * ROWS;              // y0 % 8 == 0 -> slot(r) = r & 7
    const size_t imgoff = (size_t)blockIdx.y * (size_t)(W * H);
    const float* img  = in  + imgoff;
    float*       outp = out + imgoff;

    const float PINF = __builtin_inff();
    const float NINF = -__builtin_inff();
    const bool has_l = (c0 > 0);
    const bool has_r = (c0 + 4 < W);

    const int q = t >> 6;                    // wave id: wave q stages quarter q

    // Stage row r (clamped) into ring slot: one global_load_lds per wave,
    // LDS dest = wave-uniform base + lane*16 (linear), global src matches.
    auto stage = [&](int r, int slot) {
        int rc = r < 0 ? 0 : (r > H - 1 ? H - 1 : r);
        const float* gp = img + (size_t)rc * W + c0;          // 16B per lane
        float* lp = &smem[slot][q * 256];                     // wave-uniform
        __builtin_amdgcn_global_load_lds(gp, lp, 16, 0, 0);
    };

    // Horizontal 3-min of staged row -> hm[0..5] at positions c0-1..c0+4.
    // OOB rows (clamped duplicates in LDS) masked to +inf here.
    auto hminLDS = [&](int r, int slot, float hm[6]) {
        const float* rowp = &smem[slot][0];
        const bool rok = (r >= 0) && (r <= H - 1);
        f4 m  = *(const f4*)(rowp + c0);                      // ds_read_b128
        f2 L  = *(const f2*)(rowp + (has_l ? c0 - 2 : 0));    // ds_read_b64
        f2 Rr = *(const f2*)(rowp + (has_r ? c0 + 4 : W - 2));
        const float x0 = has_l ? L.x : PINF;
        const float x1 = has_l ? L.y : PINF;
        const float x2 = m.x, x3 = m.y, x4 = m.z, x5 = m.w;
        const float x6 = has_r ? Rr.x : PINF;
        const float x7 = has_r ? Rr.y : PINF;
        hm[0] = rok ? fminf(fminf(x0, x1), x2) : PINF;
        hm[1] = rok ? fminf(fminf(x1, x2), x3) : PINF;
        hm[2] = rok ? fminf(fminf(x2, x3), x4) : PINF;
        hm[3] = rok ? fminf(fminf(x3, x4), x5) : PINF;
        hm[4] = rok ? fminf(fminf(x4, x5), x6) : PINF;
        hm[5] = rok ? fminf(fminf(x5, x6), x7) : PINF;
    };

    // Erosion row r at positions c0-1..c0+4; OOB row/col positions -> -inf.
    auto erow = [&](int r, const float a[6], const float b[6], const float c[6], float e[6]) {
        const bool eok = (r >= 0) && (r <= H - 1);
        #pragma unroll
        for (int i = 0; i < 6; i++) {
            float v = fminf(fminf(a[i], b[i]), c[i]);
            e[i] = eok ? v : NINF;
        }
        if (!has_l) e[0] = NINF;
        if (!has_r) e[5] = NINF;
    };

    auto hmax4 = [&](const float e[6], float hx[4]) {
        #pragma unroll
        for (int i = 0; i < 4; i++) hx[i] = fmaxf(fmaxf(e[i], e[i + 1]), e[i + 2]);
    };

    // ---- prologue: stage rows y0-2..y0+5 into slots 6,7,0,1,2,3,4,5 ----
    stage(y0 - 2, 6); stage(y0 - 1, 7);
    stage(y0 + 0, 0); stage(y0 + 1, 1);
    stage(y0 + 2, 2); stage(y0 + 3, 3);
    stage(y0 + 4, 4); stage(y0 + 5, 5);
    WAITV(4);                                // rows y0-2..y0+1 resident
    BAR();

    float hmA[6], hmB[6], hmC[6], hmD[6];
    hminLDS(y0 - 2, 6, hmA); hminLDS(y0 - 1, 7, hmB);
    hminLDS(y0,     0, hmC); hminLDS(y0 + 1, 1, hmD);
    float e[6], hx0[4], hx1[4], hx2[4];
    erow(y0 - 1, hmA, hmB, hmC, e); hmax4(e, hx0);
    erow(y0,     hmB, hmC, hmD, e); hmax4(e, hx1);
    float hmP[6], hmQ[6], hmR[6];
    #pragma unroll
    for (int i = 0; i < 6; i++) { hmP[i] = hmC[i]; hmQ[i] = hmD[i]; }

    // ---- main loop: stage(y+6) -> counted wait -> barrier -> consume(y+2) ----
    #pragma unroll
    for (int k = 0; k < ROWS; k++) {
        const int y = y0 + k;
        int rn = y + 6;                      // tail: re-stage last row (never
        if (rn > y0 + ROWS + 1) rn = y0 + ROWS + 1;   // read) for uniform count
        stage(rn, (k + 6) & 7);

        if (k == 0)      WAITV(4);           // row y+2 staged 4 iters ago
        else if (k == 1) WAITV(5);
        else if (k == 2) WAITV(6);
        else if (k == 3) WAITV(7);
        else             WAITV(8);
        BAR();

        hminLDS(y + 2, (k + 2) & 7, hmR);
        erow(y + 1, hmP, hmQ, hmR, e);
        hmax4(e, hx2);

        f4 o;
        o.x = fmaxf(fmaxf(hx0[0], hx1[0]), hx2[0]);
        o.y = fmaxf(fmaxf(hx0[1], hx1[1]), hx2[1]);
        o.z = fmaxf(fmaxf(hx0[2], hx1[2]), hx2[2]);
        o.w = fmaxf(fmaxf(hx0[3], hx1[3]), hx2[3]);
        *(f4*)(outp + (size_t)y * W + c0) = o;   // regular cached store (the A/B)

        #pragma unroll
        for (int i = 0; i < 4; i++) { hx0[i] = hx1[i]; hx1[i] = hx2[i]; }
        #pragma unroll
        for (int i = 0; i < 6; i++) { hmP[i] = hmQ[i]; hmQ[i] = hmR[i]; }
    }
}

extern "C" void kernel_launch(void* const* d_in, const int* in_sizes, int n_in,
                              void* d_out, int out_size, void* d_ws, size_t ws_size,
                              hipStream_t stream) {
    const float* x = (const float*)d_in[0];
    float* out = (float*)d_out;
    // 16 batch * 3 channels = 48 images; 64 row-tiles per image -> 3072 blocks
    dim3 grid(NTILE, 48);
    dim3 block(NT);
    open3x3_v10<<<grid, block, 0, stream>>>(x, out);
}